// Round 1
// baseline (213.481 us; speedup 1.0000x reference)
//
#include <hip/hip_runtime.h>
#include <math.h>

#define NTOK 4096
#define IND 768
#define DD 256
#define DD2 512
#define DD4 64
#define DHH 128

__device__ __forceinline__ float gelu_f(float x) {
    return 0.5f * x * (1.0f + erff(x * 0.70710678118654752440f));
}

// block-wide sum for 256 threads (4 waves); lds must have >= 4 floats
__device__ __forceinline__ float block_sum(float v, float* lds) {
    #pragma unroll
    for (int o = 32; o > 0; o >>= 1) v += __shfl_down(v, o);
    int lane = threadIdx.x & 63, w = threadIdx.x >> 6;
    if (lane == 0) lds[w] = v;
    __syncthreads();
    float r = lds[0] + lds[1] + lds[2] + lds[3];
    __syncthreads();
    return r;
}

// ---- kernel 0: token-independent spatial_feat / level_feat ----
__global__ __launch_bounds__(64) void k_const(
    const float* __restrict__ spw1, const float* __restrict__ spb1,
    const float* __restrict__ spw2, const float* __restrict__ spb2,
    const float* __restrict__ lw1, const float* __restrict__ lb1,
    const float* __restrict__ lw2, const float* __restrict__ lb2,
    const int* __restrict__ levels, const int* __restrict__ ph, const int* __restrict__ pw,
    float* __restrict__ constf /*128 floats: [0:64] spatial, [64:128] level*/) {
    __shared__ float hs[64], hl[64];
    int t = threadIdx.x;
    float p0 = (float)ph[0], p1 = (float)pw[0];
    float lvl = (float)levels[0];
    hs[t] = fmaxf(0.f, p0 * spw1[t] + p1 * spw1[64 + t] + spb1[t]);
    hl[t] = fmaxf(0.f, lvl * lw1[t] + lb1[t]);
    __syncthreads();
    float a = spb2[t], b = lb2[t];
    for (int j = 0; j < 64; ++j) {
        a += hs[j] * spw2[j * 64 + t];
        b += hl[j] * lw2[j * 64 + t];
    }
    constf[t] = a;
    constf[64 + t] = b;
}

// ---- kernel A: per-token LN, stats, edge, stats/edge MLPs, enh_in assembly ----
__global__ __launch_bounds__(256) void k_stats(
    const float* __restrict__ tokens,
    const float* __restrict__ ln_g, const float* __restrict__ ln_b,
    const float* __restrict__ sw1, const float* __restrict__ sb1,
    const float* __restrict__ sw2, const float* __restrict__ sb2,
    const float* __restrict__ ew1, const float* __restrict__ eb1,
    const float* __restrict__ ew2, const float* __restrict__ eb2,
    const float* __restrict__ constf,
    float* __restrict__ x_ln, float* __restrict__ enh_in) {
    int n = blockIdx.x, t = threadIdx.x;
    const float* x = tokens + (size_t)n * IND;
    __shared__ float red[4];
    float v[3];
    float s = 0.f, s2 = 0.f, es = 0.f;
    #pragma unroll
    for (int i = 0; i < 3; ++i) {
        int e = t + i * 256;
        float xv = x[e];
        v[i] = xv;
        s += xv; s2 += xv * xv;
        if (e > 0) es += fabsf(xv - x[e - 1]);
    }
    s  = block_sum(s, red);
    s2 = block_sum(s2, red);
    es = block_sum(es, red);
    float mean = s * (1.f / 768.f);
    float var_b = s2 * (1.f / 768.f) - mean * mean;
    float var_u = (s2 - 768.f * mean * mean) * (1.f / 767.f);
    float rstd = rsqrtf(var_b + 1e-5f);
    float edge = es * (1.f / 767.f);
    #pragma unroll
    for (int i = 0; i < 3; ++i) {
        int e = t + i * 256;
        x_ln[(size_t)n * IND + e] = (v[i] - mean) * rstd * ln_g[e] + ln_b[e];
    }
    __shared__ float hid[128];
    if (t < 64) {
        hid[t] = fmaxf(0.f, var_u * sw1[t] + mean * sw1[64 + t] + sb1[t]);
    } else if (t < 128) {
        int j = t - 64;
        hid[64 + j] = fmaxf(0.f, edge * ew1[j] + eb1[j]);
    }
    __syncthreads();
    float* er = enh_in + (size_t)n * DD;
    if (t < 64) {
        float a = sb2[t];
        for (int j = 0; j < 64; ++j) a += hid[j] * sw2[j * 64 + t];
        er[t] = a;
    } else if (t < 128) {
        int k = t - 64;
        float a = eb2[k];
        for (int j = 0; j < 64; ++j) a += hid[64 + j] * ew2[j * 64 + k];
        er[64 + k] = a;
    } else {
        er[t] = constf[t - 128];
    }
}

// ---- tiled fp32 GEMM: C[M,N] = A[M,K] @ B[K,N] + bias; epi 0=none 1=gelu 2=+emb[idx] ----
__global__ __launch_bounds__(256) void k_gemm(
    const float* __restrict__ A, const float* __restrict__ B,
    const float* __restrict__ bias, float* __restrict__ C,
    int M, int N, int K, int epi,
    const int* __restrict__ levels, const float* __restrict__ emb) {
    __shared__ float As[16][64];  // [k][m]
    __shared__ float Bs[16][64];  // [k][n]
    int tid = threadIdx.x;
    int bm = blockIdx.y * 64, bn = blockIdx.x * 64;
    int tx = tid & 15, ty = tid >> 4;
    float acc[4][4] = {};
    for (int k0 = 0; k0 < K; k0 += 16) {
        {
            int r = tid >> 2, c4 = (tid & 3) * 4;
            float4 av = *(const float4*)(A + (size_t)(bm + r) * K + k0 + c4);
            As[c4 + 0][r] = av.x; As[c4 + 1][r] = av.y;
            As[c4 + 2][r] = av.z; As[c4 + 3][r] = av.w;
        }
        {
            int rb = tid >> 4, cb = (tid & 15) * 4;
            *(float4*)&Bs[rb][cb] = *(const float4*)(B + (size_t)(k0 + rb) * N + bn + cb);
        }
        __syncthreads();
        #pragma unroll
        for (int k = 0; k < 16; ++k) {
            float4 a4 = *(const float4*)&As[k][ty * 4];
            float4 b4 = *(const float4*)&Bs[k][tx * 4];
            float a[4] = {a4.x, a4.y, a4.z, a4.w};
            float b[4] = {b4.x, b4.y, b4.z, b4.w};
            #pragma unroll
            for (int i = 0; i < 4; ++i)
                #pragma unroll
                for (int j = 0; j < 4; ++j)
                    acc[i][j] += a[i] * b[j];
        }
        __syncthreads();
    }
    #pragma unroll
    for (int i = 0; i < 4; ++i) {
        int m = bm + ty * 4 + i;
        #pragma unroll
        for (int j = 0; j < 4; ++j) {
            int n = bn + tx * 4 + j;
            float vv = acc[i][j] + bias[n];
            if (epi == 1) {
                vv = gelu_f(vv);
            } else if (epi == 2) {
                int id = min(max(levels[m * 2], 0), 50);
                vv += emb[(size_t)id * N + n];
            }
            C[(size_t)m * N + n] = vv;
        }
    }
}

// ---- kernel F: enh LN+gelu fold, per-token expert GEMM, LN+gelu, gate, out ----
__global__ __launch_bounds__(256) void k_adapter(
    const float* __restrict__ h, const float* __restrict__ e_pre,
    const float* __restrict__ fg, const float* __restrict__ fbeta,
    const float* __restrict__ aW, const float* __restrict__ ab,
    const float* __restrict__ ag, const float* __restrict__ abt,
    const float* __restrict__ dw1, const float* __restrict__ db1,
    const float* __restrict__ dw2, const float* __restrict__ db2,
    const int* __restrict__ levels, float* __restrict__ out) {
    int n = blockIdx.x, f = threadIdx.x;
    __shared__ float red[4];
    __shared__ float hs[256];
    __shared__ float ys[256];
    __shared__ float wred[2];
    int idx = min(max(levels[n * 2], 0), 50);
    // enh = gelu(LN(e_pre; fg, fbeta)); hfull = h + 0.3*enh
    float e = e_pre[(size_t)n * DD + f];
    float s  = block_sum(e, red);
    float s2 = block_sum(e * e, red);
    float mean = s * (1.f / 256.f);
    float var = s2 * (1.f / 256.f) - mean * mean;
    float rstd = rsqrtf(var + 1e-5f);
    float enh = gelu_f((e - mean) * rstd * fg[f] + fbeta[f]);
    hs[f] = h[(size_t)n * DD + f] + 0.3f * enh;
    __syncthreads();
    // y = hfull @ aW[idx] + ab[idx]
    const float* W = aW + (size_t)idx * DD * DD;
    float acc = ab[(size_t)idx * DD + f];
    #pragma unroll 8
    for (int d = 0; d < DD; ++d) acc += hs[d] * W[(size_t)d * DD + f];
    // y = gelu(LN(y; ag[idx], abt[idx]))
    float ss  = block_sum(acc, red);
    float ss2 = block_sum(acc * acc, red);
    float m2 = ss * (1.f / 256.f);
    float v2 = ss2 * (1.f / 256.f) - m2 * m2;
    float r2 = rsqrtf(v2 + 1e-5f);
    float y = gelu_f((acc - m2) * r2 * ag[(size_t)idx * DD + f] + abt[(size_t)idx * DD + f]);
    ys[f] = y;
    __syncthreads();
    // gate: w = sigmoid(relu(y@dw1+db1)@dw2+db2)
    float part = 0.f;
    if (f < DHH) {
        float hv = db1[f];
        #pragma unroll 8
        for (int d = 0; d < DD; ++d) hv += ys[d] * dw1[(size_t)d * DHH + f];
        hv = fmaxf(hv, 0.f);
        part = hv * dw2[f];
    }
    #pragma unroll
    for (int o = 32; o > 0; o >>= 1) part += __shfl_down(part, o);
    int lane = f & 63, w = f >> 6;
    if (lane == 0 && w < 2) wred[w] = part;
    __syncthreads();
    float wp = wred[0] + wred[1] + db2[0];
    float gate = 0.8f + 0.4f / (1.f + expf(-wp));
    out[(size_t)n * DD + f] = y * gate;
}

extern "C" void kernel_launch(void* const* d_in, const int* in_sizes, int n_in,
                              void* d_out, int out_size, void* d_ws, size_t ws_size,
                              hipStream_t stream) {
    const float* tokens = (const float*)d_in[0];
    const float* ln_g = (const float*)d_in[1];
    const float* ln_b = (const float*)d_in[2];
    const float* pw1 = (const float*)d_in[3];
    const float* pb1 = (const float*)d_in[4];
    const float* pw2 = (const float*)d_in[5];
    const float* pb2 = (const float*)d_in[6];
    const float* emb = (const float*)d_in[7];
    const float* sw1 = (const float*)d_in[8];
    const float* sb1 = (const float*)d_in[9];
    const float* sw2 = (const float*)d_in[10];
    const float* sb2 = (const float*)d_in[11];
    const float* ew1 = (const float*)d_in[12];
    const float* eb1 = (const float*)d_in[13];
    const float* ew2 = (const float*)d_in[14];
    const float* eb2 = (const float*)d_in[15];
    const float* spw1 = (const float*)d_in[16];
    const float* spb1 = (const float*)d_in[17];
    const float* spw2 = (const float*)d_in[18];
    const float* spb2 = (const float*)d_in[19];
    const float* lw1 = (const float*)d_in[20];
    const float* lb1 = (const float*)d_in[21];
    const float* lw2 = (const float*)d_in[22];
    const float* lb2 = (const float*)d_in[23];
    const float* fw = (const float*)d_in[24];
    const float* fb = (const float*)d_in[25];
    const float* fg = (const float*)d_in[26];
    const float* fbeta = (const float*)d_in[27];
    const float* aW = (const float*)d_in[28];
    const float* ab = (const float*)d_in[29];
    const float* ag = (const float*)d_in[30];
    const float* abt = (const float*)d_in[31];
    const float* dw1 = (const float*)d_in[32];
    const float* db1 = (const float*)d_in[33];
    const float* dw2 = (const float*)d_in[34];
    const float* db2 = (const float*)d_in[35];
    const int* levels = (const int*)d_in[36];
    const int* ph = (const int*)d_in[37];
    const int* pw = (const int*)d_in[38];
    float* outp = (float*)d_out;

    float* ws = (float*)d_ws;
    float* x_ln  = ws;                               // 4096*768
    float* h1    = x_ln + (size_t)NTOK * IND;        // 4096*512
    float* h     = h1 + (size_t)NTOK * DD2;          // 4096*256
    float* enh_in = h + (size_t)NTOK * DD;           // 4096*256
    float* e_pre = enh_in + (size_t)NTOK * DD;       // 4096*256
    float* constf = e_pre + (size_t)NTOK * DD;       // 128

    k_const<<<1, 64, 0, stream>>>(spw1, spb1, spw2, spb2, lw1, lb1, lw2, lb2,
                                  levels, ph, pw, constf);
    k_stats<<<NTOK, 256, 0, stream>>>(tokens, ln_g, ln_b, sw1, sb1, sw2, sb2,
                                      ew1, eb1, ew2, eb2, constf, x_ln, enh_in);
    // h1 = gelu(x_ln @ pw1 + pb1)
    k_gemm<<<dim3(DD2 / 64, NTOK / 64), 256, 0, stream>>>(
        x_ln, pw1, pb1, h1, NTOK, DD2, IND, 1, nullptr, nullptr);
    // h = h1 @ pw2 + pb2 + emb[idx]
    k_gemm<<<dim3(DD / 64, NTOK / 64), 256, 0, stream>>>(
        h1, pw2, pb2, h, NTOK, DD, DD2, 2, levels, emb);
    // e_pre = enh_in @ fw + fb
    k_gemm<<<dim3(DD / 64, NTOK / 64), 256, 0, stream>>>(
        enh_in, fw, fb, e_pre, NTOK, DD, DD, 0, nullptr, nullptr);
    k_adapter<<<NTOK, 256, 0, stream>>>(h, e_pre, fg, fbeta, aW, ab, ag, abt,
                                        dw1, db1, dw2, db2, levels, outp);
}